// Round 5
// baseline (171.507 us; speedup 1.0000x reference)
//
#include <hip/hip_runtime.h>
#include <math.h>

#define Bq 4
#define Hh 16
#define Lq 1024
#define Dd 64
#define Kk 8
#define QT 64         // q rows per block (32 per wave pair; qw in {0,1})
#define KT 128        // k rows per iteration; sw splits into 2x64
#define FMAX 8.0f     // fixed softmax shift (verified safe R1-R13)
#define LOG2E 1.44269504f

typedef __attribute__((ext_vector_type(8))) short short8;         // 8 bf16
typedef __attribute__((ext_vector_type(4))) unsigned int u32x4;   // 4 dwords
typedef __attribute__((ext_vector_type(16))) float f32x16;

// packed f32x2 -> bf16x2, round-half-up — BIT-IDENTICAL to R5's f2bh
// ((u+0x8000)>>16) but 3 VALU ops/pair via v_perm_b32 byte select.
// R9 post-mortem: __float22bfloat162_rn + reinterpret_cast took a local's
// address -> un-promoted alloca -> ~110 MB scratch traffic. Pure int ops only.
__device__ __forceinline__ unsigned int pk2(float a, float b) {
    return __builtin_amdgcn_perm(__float_as_uint(b) + 0x8000u,
                                 __float_as_uint(a) + 0x8000u,
                                 0x07060302u);
}

// j-permutation (verified R4-R13): V row j -> column slot so the S^T C/D
// register layout IS the PV A-fragment layout (P never touches LDS).
// Low 2 bits map identity: jperm(j0+i) == jperm(j0)+i for j0%4==0, i<4.
__device__ __forceinline__ int jperm(int j) {
    return (j & 32) | ((j & 8) << 1) | ((j & 4) << 1) | ((j & 16) >> 2) | (j & 3);
}

// ---------------------------------------------------------------------------
// R14 pre-pass: fragment-major bf16 K/V + full bias table, ONCE per launch.
//   Kf[bh][g][half][c][h5][l31][e] = bf16(K[bh][64g+32half+l31][16c+8h5+e])
//     flat: bh<<16 | g<<12 | half<<11 | (2c+h5)<<8 | l31*8 + e      (8 MiB)
//   Vf[bh][g][c][h5][nb][l31][e]: slot-chunk (16c+8h5+e) of jperm'd V^T,
//     row d = 32nb+l31:  bh<<16 | g<<12 | (2c+h5)<<9 | nb<<8 | (d&31)*8 + e
//     (8 MiB).  Values bit-identical to R13's LDS contents (same pk2 path).
//   tab[phi][h][i2] (4 x 16 x 2048 floats, 512 KiB): phase-shifted copies of
//     biasv(h, rel = i2+phi-1023) = (log(ksum+eps+bp) - |rel|*slope - FMAX)
//     *log2e  -> main kernel reads aligned float4 regardless of lane offset.
// Every MFMA fragment in the main loop becomes ONE 64-lane x 16 B contiguous
// global load (8 cachelines) — fixes R12's fatal 64-lines-per-V-load.
// ---------------------------------------------------------------------------
__global__ __launch_bounds__(256) void conv_kernel(
    const float* __restrict__ kp, const float* __restrict__ vp,
    const float* __restrict__ off, const float* __restrict__ amp,
    const float* __restrict__ sh, const float* __restrict__ bpar,
    unsigned short* __restrict__ kf, unsigned short* __restrict__ vt,
    float* __restrict__ tab)
{
    const int tid = blockIdx.x * 256 + threadIdx.x;
    // ---- Kf: 2 tasks/thread; read 8 rows x 256 B contiguous per wave ----
    #pragma unroll
    for (int it = 0; it < 2; ++it) {
        int tau = it * 262144 + tid;          // < 524288
        int row = tau >> 3;                   // bh*1024 + j
        int ch  = tau & 7;                    // 2c + h5
        const float* src = kp + (size_t)row * Dd + ch * 8;
        float4 x0 = *(const float4*)(src);
        float4 x1 = *(const float4*)(src + 4);
        u32x4 a;
        a[0] = pk2(x0.x, x0.y); a[1] = pk2(x0.z, x0.w);
        a[2] = pk2(x1.x, x1.y); a[3] = pk2(x1.z, x1.w);
        int bh = row >> 10, jj = row & 1023;
        int g = jj >> 6, half = (jj >> 5) & 1, l31 = jj & 31;
        *(u32x4*)(kf + ((size_t)bh << 16) + (g << 12) + (half << 11)
                     + (ch << 8) + l31 * 8) = a;
    }
    // ---- Vf: 4x4 micro-transpose (same pairing as R13 staging) ----
    {
        const int bh = tid >> 12;
        const int dt = (tid >> 8) & 15;
        const int jt = tid & 255;
        const int j0 = 4 * jt;
        const float* vsrc = vp + ((size_t)bh * Lq + j0) * Dd + 4 * dt;
        float4 r0 = *(const float4*)(vsrc);
        float4 r1 = *(const float4*)(vsrc + Dd);
        float4 r2 = *(const float4*)(vsrc + 2 * Dd);
        float4 r3 = *(const float4*)(vsrc + 3 * Dd);
        const int g  = j0 >> 6;
        const int sc = jperm(j0 & 63);        // sc%4==0 -> e0 in {0,4}
        const int ch = sc >> 3;               // 2c + h5
        const int e0 = sc & 7;
        #pragma unroll
        for (int cc = 0; cc < 4; ++cc) {
            int d = 4 * dt + cc;
            uint2 wv;
            wv.x = pk2(((const float*)&r0)[cc], ((const float*)&r1)[cc]);
            wv.y = pk2(((const float*)&r2)[cc], ((const float*)&r3)[cc]);
            *(uint2*)(vt + ((size_t)bh << 16) + (g << 12) + (ch << 9)
                         + ((d >> 5) << 8) + (d & 31) * 8 + e0) = wv;
        }
    }
    // ---- bias table: 4 phase copies ----
    if (tid < 131072) {
        int phi = tid >> 15, rem = tid & 32767;
        int h = rem >> 11, i2 = rem & 2047;
        int reli = i2 + phi - 1023;
        if (reli > 1023) reli = 1023;         // pad slots, never read
        float rel = (float)reli;
        float slope = (h < Hh - 2) ? 4.605170185988092f * exp2f(-6.0f * (float)h / 13.0f) : 0.0f;
        float ksum = 0.0f;
        #pragma unroll
        for (int kk = 0; kk < Kk; ++kk) {
            float a = amp[kk * Hh + h];
            float o = off[kk * Hh + h];
            float s = sh[kk * Hh + h];
            float sgn = (a > 0.0f) ? 1.0f : ((a < 0.0f) ? -1.0f : 0.0f);
            ksum += fabsf(a) / (1.0f + __expf(-sgn * (rel - o) / s));
        }
        tab[tid] = (logf(ksum + 1e-8f + bpar[h]) - fabsf(rel) * slope - FMAX) * LOG2E;
    }
}

// ---------------------------------------------------------------------------
// R14 main: ZERO barriers, ZERO LDS in the K-loop.  Every fragment is a
// coalesced 1 KB wave-load from the fragment-major workspace (L1/L2-hot:
// ~2.1 MB per XCD, bh%8 XCD pinning; qw-pair waves reuse identical frags
// via L1).  Removes vs R13: 2 barriers+drains/iter, 8 ds_write_b128/iter,
// 16 ds_read_b128/iter, K/V bank conflicts, prefetch registers, and the
// whole transcendental bias prologue.  Waves fully independent -> the 4
// waves/SIMD (VGPR ceiling; 8/SIMD needs <=64 VGPR, impossible here) can
// slide phases freely instead of summing pipe-by-pipe.
// Block = 256 (4 waves), grid (64 bh, 16 qt).  Wave w: qw=w>>1, sw=w&1.
// mfma_f32_32x32x16_bf16.  S^T = K Q^T, C/D: col=lane&31 (=i q-row),
// row=(r&3)+8*(r>>2)+4*(lane>>5) (=j_loc).  O = P V via jperm trick.
// Bias = MFMA C-init from global table (aligned float4 via 4-copy phase).
// Fixed-max softmax: p = exp2(S + (bias-FMAX)*log2e), Q pre-scaled 0.125*log2e.
// __launch_bounds__(256,2): 128-VGPR cap; NEVER arg=4 (R6/R7: 64-cap, spills).
// ---------------------------------------------------------------------------
__global__ __launch_bounds__(256, 2) void attn_kernel(
    const float* __restrict__ qp,
    const unsigned short* __restrict__ kf,
    const unsigned short* __restrict__ vt,
    const float* __restrict__ tab,
    float* __restrict__ out)
{
    __shared__ __align__(16) float red[4 * 64 * 17];   // epilogue scratch ONLY

    const int bh = blockIdx.x;            // fastest -> XCD = bh%8
    const int qs = blockIdx.y * QT;
    const int t  = threadIdx.x;
    const int w  = t >> 6;                // 0..3
    const int qw = w >> 1;                // q sub-block 0/1
    const int sw = w & 1;                 // k sub-tile 0/1
    const int lane = t & 63;
    const int l31 = lane & 31;
    const int h5  = lane >> 5;
    const int h   = bh & 15;

    // ---- Q B-frags (global, once), scale folded, packed converts ----
    const float QS = 0.125f * LOG2E;
    short8 bq[4];
    const float* qrow = qp + ((size_t)bh * Lq + qs + 32 * qw + l31) * Dd;
    #pragma unroll
    for (int c = 0; c < 4; ++c) {
        float4 x0 = *(const float4*)(qrow + c * 16 + h5 * 8);
        float4 x1 = *(const float4*)(qrow + c * 16 + h5 * 8 + 4);
        u32x4 a;
        a[0] = pk2(x0.x * QS, x0.y * QS);
        a[1] = pk2(x0.z * QS, x0.w * QS);
        a[2] = pk2(x1.x * QS, x1.y * QS);
        a[3] = pk2(x1.z * QS, x1.w * QS);
        bq[c] = __builtin_bit_cast(short8, a);
    }

    // ---- lane-folded fragment base pointers (16B-aligned dwordx4) ----
    // K frag (half hf, step c):  kfl + kt*8192 + hf*2048 + c*512
    // V frag (nb, step c):       vfl + kt*8192 + nb*256  + c*1024
    const unsigned short* kfl = kf + (((size_t)bh << 16) + (sw << 12)) + h5 * 256 + l31 * 8;
    const unsigned short* vfl = vt + (((size_t)bh << 16) + (sw << 12)) + h5 * 512 + l31 * 8;

    // ---- bias addressing: i_tab = (k_abs - q_abs) + 1023 ----
    const int L0g = 4 * h5 - 32 * qw - l31 + 1023 - qs;
    const int phi = L0g & 3;              // ks,64sw,8p all ≡ 0 mod 4
    const float* bcopy = tab + phi * 32768 + h * 2048 - phi;  // aligned view

    // ---- accumulators (partial over this wave's k sub-tiles) ----
    f32x16 O0, O1;
    #pragma unroll
    for (int r = 0; r < 16; ++r) { O0[r] = 0.f; O1[r] = 0.f; }
    float l_part = 0.0f;

    #pragma unroll 1
    for (int kt = 0; kt < Lq / KT; ++kt) {        // 8 iterations, NO barriers
        const size_t ko = (size_t)kt << 13;       // 8192 shorts per k-128

        // ---- K fragment loads (8 x coalesced 1 KB) ----
        short8 ka0[4], ka1[4];
        #pragma unroll
        for (int c = 0; c < 4; ++c) {
            ka0[c] = *(const short8*)(kfl + ko + c * 512);
            ka1[c] = *(const short8*)(kfl + ko + 2048 + c * 512);
        }

        // ---- S init = bias (MFMA C-in), aligned float4 from global ----
        f32x16 S0, S1;
        #pragma unroll
        for (int p = 0; p < 4; ++p) {
            int base0 = kt * KT + 64 * sw + 8 * p + L0g;
            float4 b0 = *(const float4*)(bcopy + base0);
            float4 b1 = *(const float4*)(bcopy + base0 + 32);
            S0[4 * p + 0] = b0.x; S0[4 * p + 1] = b0.y;
            S0[4 * p + 2] = b0.z; S0[4 * p + 3] = b0.w;
            S1[4 * p + 0] = b1.x; S1[4 * p + 1] = b1.y;
            S1[4 * p + 2] = b1.z; S1[4 * p + 3] = b1.w;
        }

        // ---- S^T = K Q^T + bias ----
        #pragma unroll
        for (int c = 0; c < 4; ++c)
            S0 = __builtin_amdgcn_mfma_f32_32x32x16_bf16(ka0[c], bq[c], S0, 0, 0, 0);
        #pragma unroll
        for (int c = 0; c < 4; ++c)
            S1 = __builtin_amdgcn_mfma_f32_32x32x16_bf16(ka1[c], bq[c], S1, 0, 0, 0);

        // ---- V fragment loads issued BEFORE softmax (latency hides) ----
        short8 vf0[4], vf1[4];
        #pragma unroll
        for (int c = 0; c < 4; ++c) {
            vf0[c] = *(const short8*)(vfl + ko + c * 1024);
            vf1[c] = *(const short8*)(vfl + ko + 256 + c * 1024);
        }

        // ---- softmax: p = exp2(S) (bias already inside) ----
        float lsum = 0.0f;
        #pragma unroll
        for (int r = 0; r < 16; ++r) {
            float e0 = __builtin_amdgcn_exp2f(S0[r]);
            float e1 = __builtin_amdgcn_exp2f(S1[r]);
            S0[r] = e0; S1[r] = e1;
            lsum += e0 + e1;
        }
        l_part += lsum;

        // ---- P A-frags in-register (jperm trick), packed converts ----
        short8 ap[4];
        #pragma unroll
        for (int c = 0; c < 4; ++c) {
            int b = (c & 1) * 4;
            u32x4 a;
            if (c >> 1) {
                a[0] = pk2(S1[b + 0], S1[b + 1]);
                a[1] = pk2(S1[b + 2], S1[b + 3]);
                a[2] = pk2(S1[b + 8], S1[b + 9]);
                a[3] = pk2(S1[b + 10], S1[b + 11]);
            } else {
                a[0] = pk2(S0[b + 0], S0[b + 1]);
                a[1] = pk2(S0[b + 2], S0[b + 3]);
                a[2] = pk2(S0[b + 8], S0[b + 9]);
                a[3] = pk2(S0[b + 10], S0[b + 11]);
            }
            ap[c] = __builtin_bit_cast(short8, a);
        }

        // ---- O += P V ----
        #pragma unroll
        for (int c = 0; c < 4; ++c)
            O0 = __builtin_amdgcn_mfma_f32_32x32x16_bf16(ap[c], vf0[c], O0, 0, 0, 0);
        #pragma unroll
        for (int c = 0; c < 4; ++c)
            O1 = __builtin_amdgcn_mfma_f32_32x32x16_bf16(ap[c], vf1[c], O1, 0, 0, 0);
    }

    // ---- epilogue: wave pair (qw,0)+(qw,1) combine, normalize, store ----
    // Scratch 4x64x17 floats; stride 17 dwords -> 2-way bank alias only.
    l_part += __shfl_xor(l_part, 32);     // combine j-halves within wave
    const int rb = (w * 64 + lane) * 17;
    #pragma unroll
    for (int r = 0; r < 16; ++r) red[rb + r] = sw ? O0[r] : O1[r];
    red[rb + 16] = l_part;
    __syncthreads();
    const int pb = ((w ^ 1) * 64 + lane) * 17;
    float inv = 1.0f / (l_part + red[pb + 16]);
    float* ob = out + ((size_t)bh * Lq + qs + 32 * qw) * Dd;
    #pragma unroll
    for (int r = 0; r < 16; ++r) {
        float o = (sw ? O1[r] : O0[r]) + red[pb + r];
        int rowp = (r & 3) + 8 * (r >> 2) + 4 * h5;
        float invp = __shfl(inv, rowp, 32);   // l lives at lane l31==row
        ob[(size_t)rowp * Dd + 32 * sw + l31] = o * invp;  // sw picks col half
    }
}

extern "C" void kernel_launch(void* const* d_in, const int* in_sizes, int n_in,
                              void* d_out, int out_size, void* d_ws, size_t ws_size,
                              hipStream_t stream) {
    const float* q   = (const float*)d_in[0];
    const float* k   = (const float*)d_in[1];
    const float* v   = (const float*)d_in[2];
    const float* off = (const float*)d_in[3];
    const float* amp = (const float*)d_in[4];
    const float* sh  = (const float*)d_in[5];
    const float* bp  = (const float*)d_in[6];
    float* out = (float*)d_out;

    // workspace: Kf (8 MiB) | Vf (8 MiB) | bias tab (512 KiB)
    unsigned short* kf = (unsigned short*)d_ws;
    unsigned short* vt = kf + (size_t)Bq * Hh * Lq * Dd;
    float* tab = (float*)((char*)d_ws + 16777216);

    conv_kernel<<<dim3(1024), 256, 0, stream>>>(k, v, off, amp, sh, bp, kf, vt, tab);

    dim3 grid(Bq * Hh, Lq / QT);          // (64, 16), bh fastest -> XCD locality
    attn_kernel<<<grid, 256, 0, stream>>>(q, kf, vt, tab, out);
}

// Round 6
// 122.154 us; speedup vs baseline: 1.4040x; 1.4040x over previous
//
#include <hip/hip_runtime.h>
#include <math.h>

#define Bq 4
#define Hh 16
#define Lq 1024
#define Dd 64
#define Kk 8
#define QT 128        // q rows per block (32 per wave, 4 waves)
#define KT 128        // k rows per iteration = 2 sub-tiles of 64
#define SRk 72        // K LDS row stride (bf16 elems)
#define SRv 136       // V^T LDS row stride (128 cols + pad)
#define TB 1152       // bias table entries per copy (4 shifted copies)
#define FMAX 8.0f     // fixed softmax shift (verified safe R1-R14)
#define LOG2E 1.44269504f

typedef __attribute__((ext_vector_type(8))) short short8;         // 8 bf16
typedef __attribute__((ext_vector_type(4))) unsigned int u32x4;   // 4 dwords
typedef __attribute__((ext_vector_type(16))) float f32x16;

// packed f32x2 -> bf16x2, round-half-up (3 VALU ops) — kept for the cold
// Q-conversion path (bit-identical to R5 staging).
__device__ __forceinline__ unsigned int pk2(float a, float b) {
    return __builtin_amdgcn_perm(__float_as_uint(b) + 0x8000u,
                                 __float_as_uint(a) + 0x8000u,
                                 0x07060302u);
}

// R15: single-instruction packed convert (RNE) for the HOT paths (P-pack +
// staging convoy): replaces 3-op pk2, saving ~128 VALU ops/thread/iter.
// D[15:0]=bf16(a), D[31:16]=bf16(b) — same lane order as pk2(a,b).
// (T12 recipe: no builtin on gfx950, inline asm required.)
__device__ __forceinline__ unsigned int cvtpk(float a, float b) {
    unsigned int r;
    asm("v_cvt_pk_bf16_f32 %0, %1, %2" : "=v"(r) : "v"(a), "v"(b));
    return r;
}

// j-permutation (verified R4-R14): V row j -> column slot so the S^T C/D
// register layout IS the PV A-fragment layout (P never touches LDS).
__device__ __forceinline__ int jperm(int j) {
    return (j & 32) | ((j & 8) << 1) | ((j & 4) << 1) | ((j & 16) >> 2) | (j & 3);
}

// ---------------------------------------------------------------------------
// R15 = R0 (best measured bench: 124.9 us) + four local VALU-thinning grafts.
// R12/R14 closed the VMEM-fragment direction (L1-BW-bound); R10-R13 showed
// restructured single-kernels never beat R0's warm mean; 2-kernel variants
// pay ~28 us serial conv on the bench metric.  So: keep R0's structure
// (block=256, 4 waves, QT=128, 2 blocks/CU, LDS frags, 2 barriers/iter):
//   1. bias as MFMA C-init (verified R11-R14)      -> -64 v_add/iter
//   2. row-sum l via ones-MFMA into Lacc           -> -64 v_add/iter,
//      epilogue needs NO LDS/shfl (Lacc[r] is this thread's own q-rows)
//   3. cvt_pk_bf16_f32 for P-pack + staging        -> -128 VALU ops/iter
//   4. s_setprio(1) around MFMA clusters (m191: phase-diverse waves/SIMD
//      here: 2 waves from 2 independent blocks per SIMD)
// mfma_f32_32x32x16_bf16.  Wave w owns q rows 32w..32w+31, full k128/iter.
//   S^T = K Q^T:  A = K rows (m=j), B = Q (k=d, n=i=l31).
//   C/D layout: col=lane&31 (=i), row=(r&3)+8*(r>>2)+4*(lane>>5) (=j_loc).
//   O = P V:      A = P from registers (jperm trick), B = V^T tile.
// Fixed-max softmax: p = exp2(S + (bias-FMAX)*log2e), Q pre-scaled 0.125*log2e.
// __launch_bounds__(256,2): min 2 waves/EU -> 256-VGPR cap; occupancy is
// LDS-capped at 2 blocks/CU regardless (54 KB).  NEVER arg=4 (R6/R7 spills).
// ---------------------------------------------------------------------------
__global__ __launch_bounds__(256, 2) void attn_kernel(
    const float* __restrict__ qp, const float* __restrict__ kp,
    const float* __restrict__ vp,
    const float* __restrict__ off, const float* __restrict__ amp,
    const float* __restrict__ sh, const float* __restrict__ bpar,
    float* __restrict__ out)
{
    __shared__ __align__(16) short k_s[KT * SRk];   // 18432 B  K rows [j][d]
    __shared__ __align__(16) short v_s[Dd * SRv];   // 17408 B  V^T [d][slot^swz]
    __shared__ __align__(16) float bias4[4 * TB];   // 18432 B  4 shifted copies

    const int bh = blockIdx.x;            // fastest -> XCD = bh%8
    const int qs = blockIdx.y * QT;
    const int t  = threadIdx.x;
    const int w  = t >> 6;
    const int lane = t & 63;
    const int l31 = lane & 31;
    const int h5  = lane >> 5;
    const int h   = bh & 15;

    // ---- bias copy 0: (log(ksum+eps+bp) - |rel|*slope - FMAX)*log2e ----
    float slope = (h < Hh - 2) ? 4.605170185988092f * exp2f(-6.0f * (float)h / 13.0f) : 0.0f;
    #pragma unroll
    for (int it = 0; it < 5; ++it) {
        int i = it * 256 + t;
        if (i < TB - 1) {
            float rel = (float)(i - 127 - qs);
            float ksum = 0.0f;
            #pragma unroll
            for (int kk = 0; kk < Kk; ++kk) {
                float a = amp[kk * Hh + h];
                float o = off[kk * Hh + h];
                float s = sh[kk * Hh + h];
                float sgn = (a > 0.0f) ? 1.0f : ((a < 0.0f) ? -1.0f : 0.0f);
                ksum += fabsf(a) / (1.0f + __expf(-sgn * (rel - o) / s));
            }
            bias4[i] = (logf(ksum + 1e-8f + bpar[h]) - fabsf(rel) * slope - FMAX) * LOG2E;
        }
    }

    // ---- Q B-frags (global, once), scale folded, packed converts ----
    const float QS = 0.125f * LOG2E;
    short8 bq[4];
    const float* qrow = qp + ((size_t)bh * Lq + qs + 32 * w + l31) * Dd;
    #pragma unroll
    for (int c = 0; c < 4; ++c) {
        float4 x0 = *(const float4*)(qrow + c * 16 + h5 * 8);
        float4 x1 = *(const float4*)(qrow + c * 16 + h5 * 8 + 4);
        u32x4 a;
        a[0] = pk2(x0.x * QS, x0.y * QS);
        a[1] = pk2(x0.z * QS, x0.w * QS);
        a[2] = pk2(x1.x * QS, x1.y * QS);
        a[3] = pk2(x1.z * QS, x1.w * QS);
        bq[c] = __builtin_bit_cast(short8, a);
    }

    // ---- staging geometry: thread owns 4 consecutive rows x 4 cols per sub
    const int g  = t >> 4;
    const int cl = t & 15;
    const int j0 = 4 * g;
    const int c4 = 4 * cl;
    const int vcb[2] = { jperm(j0), 64 + jperm(j0) };
    const float* kbase = kp + (size_t)bh * Lq * Dd;
    const float* vbase = vp + (size_t)bh * Lq * Dd;

    // ---- prefetch iteration 0 ----
    float4 kr[2][4], vr[2][4];
    #pragma unroll
    for (int s = 0; s < 2; ++s)
        #pragma unroll
        for (int u = 0; u < 4; ++u) {
            kr[s][u] = *(const float4*)(kbase + (size_t)(64 * s + j0 + u) * Dd + c4);
            vr[s][u] = *(const float4*)(vbase + (size_t)(64 * s + j0 + u) * Dd + c4);
        }

    __syncthreads();                      // bias copy0 visible

    // ---- replicate bias copies 1..3 (copyP[i] = bias(i+P)) ----
    #pragma unroll
    for (int it = 0; it < 5; ++it) {
        int i = it * 256 + t;
        if (i < TB) {
            float b1 = bias4[i + 1 <= TB - 2 ? i + 1 : TB - 2];
            float b2 = bias4[i + 2 <= TB - 2 ? i + 2 : TB - 2];
            float b3 = bias4[i + 3 <= TB - 2 ? i + 3 : TB - 2];
            bias4[TB + i]     = b1;
            bias4[2 * TB + i] = b2;
            bias4[3 * TB + i] = b3;
        }
    }
    // ---- write tile 0: K row-major; V reg-transposed 4x4; packed converts --
    #pragma unroll
    for (int s = 0; s < 2; ++s) {
        #pragma unroll
        for (int u = 0; u < 4; ++u) {
            uint2 kv;
            kv.x = cvtpk(kr[s][u].x, kr[s][u].y);
            kv.y = cvtpk(kr[s][u].z, kr[s][u].w);
            *(uint2*)&k_s[(64 * s + j0 + u) * SRk + c4] = kv;
        }
        #pragma unroll
        for (int cc = 0; cc < 4; ++cc) {
            int d = c4 + cc;
            uint2 vv;
            vv.x = cvtpk(((const float*)&vr[s][0])[cc], ((const float*)&vr[s][1])[cc]);
            vv.y = cvtpk(((const float*)&vr[s][2])[cc], ((const float*)&vr[s][3])[cc]);
            *(uint2*)&v_s[d * SRv + (vcb[s] ^ (8 * ((d >> 3) & 7)))] = vv;
        }
    }
    __syncthreads();

    // ---- accumulators: O, and Lacc = row-sums of P via ones-MFMA ----
    f32x16 O0, O1, Lacc;
    #pragma unroll
    for (int r = 0; r < 16; ++r) { O0[r] = 0.f; O1[r] = 0.f; Lacc[r] = 0.f; }
    short8 ones;
    #pragma unroll
    for (int e = 0; e < 8; ++e) ones[e] = (short)0x3F80;   // bf16 1.0

    const int L0 = 4 * h5 - 32 * w - l31 + 127;   // bias lane offset
    const int phi = L0 & 3;
    const float* bcopy = bias4 + phi * TB - phi;  // aligned-float4 view

    #pragma unroll 1
    for (int kt = 0; kt < Lq / KT; ++kt) {        // 8 iterations
        const int ks = kt * KT;

        // prefetch next iteration (VMEM overlaps compute below)
        if (kt < 7) {
            const float* kn = kbase + (size_t)(ks + KT) * Dd;
            const float* vn = vbase + (size_t)(ks + KT) * Dd;
            #pragma unroll
            for (int s = 0; s < 2; ++s)
                #pragma unroll
                for (int u = 0; u < 4; ++u) {
                    kr[s][u] = *(const float4*)(kn + (size_t)(64 * s + j0 + u) * Dd + c4);
                    vr[s][u] = *(const float4*)(vn + (size_t)(64 * s + j0 + u) * Dd + c4);
                }
        }

        #pragma unroll
        for (int s = 0; s < 2; ++s) {
            // ---- S init = bias (MFMA C-in), reads off the critical path ----
            f32x16 S0, S1;
            #pragma unroll
            for (int p = 0; p < 4; ++p) {
                int base0 = ks + 64 * s + 8 * p + L0;
                float4 b0 = *(const float4*)(bcopy + base0);
                float4 b1 = *(const float4*)(bcopy + base0 + 32);
                S0[4 * p + 0] = b0.x; S0[4 * p + 1] = b0.y;
                S0[4 * p + 2] = b0.z; S0[4 * p + 3] = b0.w;
                S1[4 * p + 0] = b1.x; S1[4 * p + 1] = b1.y;
                S1[4 * p + 2] = b1.z; S1[4 * p + 3] = b1.w;
            }

            // ---- S^T = K Q^T + bias (sub-tile s) ----
            __builtin_amdgcn_s_setprio(1);
            #pragma unroll
            for (int c = 0; c < 4; ++c) {
                short8 ak0 = *(const short8*)&k_s[(64 * s + l31) * SRk + c * 16 + h5 * 8];
                S0 = __builtin_amdgcn_mfma_f32_32x32x16_bf16(ak0, bq[c], S0, 0, 0, 0);
            }
            #pragma unroll
            for (int c = 0; c < 4; ++c) {
                short8 ak1 = *(const short8*)&k_s[(64 * s + 32 + l31) * SRk + c * 16 + h5 * 8];
                S1 = __builtin_amdgcn_mfma_f32_32x32x16_bf16(ak1, bq[c], S1, 0, 0, 0);
            }
            __builtin_amdgcn_s_setprio(0);

            // ---- softmax: p = exp2(S) (bias already inside, no sums) ----
            #pragma unroll
            for (int r = 0; r < 16; ++r) {
                S0[r] = __builtin_amdgcn_exp2f(S0[r]);
                S1[r] = __builtin_amdgcn_exp2f(S1[r]);
            }

            // ---- P A-frags in-register (jperm trick), single-op converts --
            short8 ap[4];
            #pragma unroll
            for (int c = 0; c < 4; ++c) {
                int b = (c & 1) * 4;
                u32x4 a;
                if (c >> 1) {
                    a[0] = cvtpk(S1[b + 0], S1[b + 1]);
                    a[1] = cvtpk(S1[b + 2], S1[b + 3]);
                    a[2] = cvtpk(S1[b + 8], S1[b + 9]);
                    a[3] = cvtpk(S1[b + 10], S1[b + 11]);
                } else {
                    a[0] = cvtpk(S0[b + 0], S0[b + 1]);
                    a[1] = cvtpk(S0[b + 2], S0[b + 3]);
                    a[2] = cvtpk(S0[b + 8], S0[b + 9]);
                    a[3] = cvtpk(S0[b + 10], S0[b + 11]);
                }
                ap[c] = __builtin_bit_cast(short8, a);
            }

            // ---- O += P V;  Lacc += P * 1 (row-sums, replaces 64 v_add) ----
            __builtin_amdgcn_s_setprio(1);
            #pragma unroll
            for (int nb = 0; nb < 2; ++nb) {
                int d = nb * 32 + l31;
                int swz = 8 * ((d >> 3) & 7);
                f32x16 acc = nb ? O1 : O0;
                #pragma unroll
                for (int c = 0; c < 4; ++c) {
                    short8 bv = *(const short8*)&v_s[d * SRv + 64 * s + ((c * 16 + h5 * 8) ^ swz)];
                    acc = __builtin_amdgcn_mfma_f32_32x32x16_bf16(ap[c], bv, acc, 0, 0, 0);
                }
                if (nb) O1 = acc; else O0 = acc;
            }
            #pragma unroll
            for (int c = 0; c < 4; ++c)
                Lacc = __builtin_amdgcn_mfma_f32_32x32x16_bf16(ap[c], ones, Lacc, 0, 0, 0);
            __builtin_amdgcn_s_setprio(0);
        }

        __syncthreads();                  // all waves done reading k_s/v_s
        if (kt < 7) {
            #pragma unroll
            for (int s = 0; s < 2; ++s) {
                #pragma unroll
                for (int u = 0; u < 4; ++u) {
                    uint2 kv;
                    kv.x = cvtpk(kr[s][u].x, kr[s][u].y);
                    kv.y = cvtpk(kr[s][u].z, kr[s][u].w);
                    *(uint2*)&k_s[(64 * s + j0 + u) * SRk + c4] = kv;
                }
                #pragma unroll
                for (int cc = 0; cc < 4; ++cc) {
                    int d = c4 + cc;
                    uint2 vv;
                    vv.x = cvtpk(((const float*)&vr[s][0])[cc], ((const float*)&vr[s][1])[cc]);
                    vv.y = cvtpk(((const float*)&vr[s][2])[cc], ((const float*)&vr[s][3])[cc]);
                    *(uint2*)&v_s[d * SRv + (vcb[s] ^ (8 * ((d >> 3) & 7)))] = vv;
                }
            }
        }
        __syncthreads();
    }

    // ---- epilogue: Lacc[r] IS the row-sum for this thread's q-row rowp(r)
    // (ones-B MFMA makes all columns equal) -> no LDS, no shfl, no barrier.
    float* ob = out + ((size_t)bh * Lq + qs) * Dd;
    #pragma unroll
    for (int r = 0; r < 16; ++r) {
        int rowp = (r & 3) + 8 * (r >> 2) + 4 * h5;
        float inv = 1.0f / Lacc[r];
        ob[(size_t)(32 * w + rowp) * Dd + l31]      = O0[r] * inv;
        ob[(size_t)(32 * w + rowp) * Dd + 32 + l31] = O1[r] * inv;
    }
}

extern "C" void kernel_launch(void* const* d_in, const int* in_sizes, int n_in,
                              void* d_out, int out_size, void* d_ws, size_t ws_size,
                              hipStream_t stream) {
    const float* q   = (const float*)d_in[0];
    const float* k   = (const float*)d_in[1];
    const float* v   = (const float*)d_in[2];
    const float* off = (const float*)d_in[3];
    const float* amp = (const float*)d_in[4];
    const float* sh  = (const float*)d_in[5];
    const float* bp  = (const float*)d_in[6];
    float* out = (float*)d_out;

    dim3 grid(Bq * Hh, Lq / QT);          // (64, 8), bh fastest -> XCD locality
    attn_kernel<<<grid, 256, 0, stream>>>(q, k, v, off, amp, sh, bp, out);
}